// Round 18
// baseline (453.146 us; speedup 1.0000x reference)
//
#include <hip/hip_runtime.h>
#include <hip/hip_bf16.h>
#include <cstdint>

#define DI __device__ __forceinline__

typedef __attribute__((ext_vector_type(16))) float f32x16;
typedef __attribute__((ext_vector_type(8)))  short bf16x8;

static constexpr int B_ = 16384, I_ = 1024, H_ = 1024;
static constexpr int M = B_;          // 16384 rows
static constexpr int N = 4 * H_;      // 4096 gate-cols (stride-32 gate permutation)
static constexpr int K = I_ + H_;     // 2048 ([x | h])
static constexpr int NT = K / 64;     // 32 K-tiles

// workspace layout (bytes)
static constexpr size_t OFF_A  = 0;                         // M*K bf16   (64 MB)
static constexpr size_t OFF_W  = OFF_A + (size_t)M * K * 2; // N*K bf16   (16 MB)
static constexpr size_t OFF_BI = OFF_W + (size_t)N * K * 2; // N f32      (16 KB)

DI unsigned short f2bf(float f) {
    union { float f; unsigned u; } v; v.f = f;
    unsigned r = v.u + 0x7FFFu + ((v.u >> 16) & 1u);
    return (unsigned short)(r >> 16);
}

// ---------------------------------------------------------------- convert
// A' = [x | h] (M x K) bf16 row-major. W' rows permuted for 32-wide tiles:
// GEMM col c -> gate = (c>>5)&3, hcol = (c>>7)*32 + (c&31).
__global__ void cvt_kernel(const float* __restrict__ x, const float* __restrict__ h,
                           const float* __restrict__ Wx, const float* __restrict__ Wh,
                           unsigned short* __restrict__ A, unsigned short* __restrict__ W)
{
    long tid = (long)blockIdx.x * blockDim.x + threadIdx.x;
    long row = tid >> 9;
    int  col = (int)(tid & 511) * 4;
    const float* src;
    unsigned short* dst;
    if (row < M) {
        src = (col < I_) ? x + (size_t)row * I_ + col
                         : h + (size_t)row * H_ + (col - I_);
        dst = A + (size_t)row * K + col;
    } else {
        int r = (int)(row - M);                 // dst row in W' = GEMM col
        int gate = (r >> 5) & 3;
        int hcol = ((r >> 7) << 5) | (r & 31);
        int srow = gate * H_ + hcol;            // src row in [4,H] stack
        src = (col < I_) ? Wx + (size_t)srow * I_ + col
                         : Wh + (size_t)srow * H_ + (col - I_);
        dst = W + (size_t)r * K + col;
    }
    float4 v = *(const float4*)src;
    ushort4 o;
    o.x = f2bf(v.x); o.y = f2bf(v.y); o.z = f2bf(v.z); o.w = f2bf(v.w);
    *(ushort4*)dst = o;
}

__global__ void bias_kernel(const float* __restrict__ bx, const float* __restrict__ bh,
                            float* __restrict__ bias)
{
    int r = blockIdx.x * blockDim.x + threadIdx.x;
    if (r < N) {
        int gate = (r >> 5) & 3;
        int hcol = ((r >> 7) << 5) | (r & 31);
        int s = gate * H_ + hcol;
        bias[r] = bx[s] + bh[s];
    }
}

// ---------------------------------------------------------------- GEMM 256x256
// FRAGMENT-MAJOR LDS + 32x32x16 MFMA. LDS holds 1KB fragments (not a 2D
// tile): frag(mt,s) of A at (mt*4+s)*512 shorts, frag(nt,s) of B likewise.
// global_load_lds SOURCE is the fragment layout (lane l -> row f*32+(l&31),
// k = s*16 + (l>>5)*8); LDS dest stays linear (HW requirement). Fragment
// reads are base + lane*16B -> consecutive banks, ZERO conflicts (fixes
// r17's structural 4-way: a 32-row b128 column read of a row-major tile
// cannot be conflict-free under any 16B-aligned swizzle).
// One vmcnt(0)+barrier per K-tile; XCD-partitioned mapping (r10).
DI void stage_frag(const unsigned short* __restrict__ g, int srow, int kbase,
                   unsigned short* lds)
{
    __builtin_amdgcn_global_load_lds(
        (const __attribute__((address_space(1))) void*)(g + (size_t)srow * K + kbase),
        (__attribute__((address_space(3))) void*)lds, 16, 0, 0);
}

DI float sigf(float v) { return 1.f / (1.f + __expf(-v)); }
DI float tanhfast(float v) {
    float vc = fminf(fmaxf(v, -15.f), 15.f);
    float e  = __expf(2.f * vc);
    return (e - 1.f) / (e + 1.f);
}

__global__ __launch_bounds__(512, 2) void gemm_lstm(
    const unsigned short* __restrict__ Abf, const unsigned short* __restrict__ Wbf,
    const float* __restrict__ bias, const float* __restrict__ c,
    float* __restrict__ out)
{
    __shared__ __align__(16) unsigned short sh[65536];   // 2 buf x (A 32KB + B 32KB)

    const int tid  = threadIdx.x;
    const int lane = tid & 63;
    const int wid  = tid >> 6;            // 0..7
    const int wr   = wid >> 1;            // 0..3  (64-row slice)
    const int wc   = wid & 1;             // 0..1  (128-col slice)

    // XCD-partitioned mapping (r10): each XCD owns 2 B-panels
    const int bid  = blockIdx.x;
    const int xcd  = bid & 7;
    const int loc  = bid >> 3;            // 0..127
    const int nbk  = (xcd << 1) | (loc & 1);   // 0..15
    const int mbk  = loc >> 1;                 // 0..63
    const int brow = mbk << 8, bcol = nbk << 8;

    const int l31  = lane & 31;
    const int skoff = (lane >> 5) << 3;   // k-offset within fragment: 0 or 8
    const int srowA = brow + (wid << 5) + l31;   // staging source rows
    const int srowB = bcol + (wid << 5) + l31;
    unsigned short* const ldsA = sh + ((wid << 2) << 9);          // 4 frags/wave
    unsigned short* const ldsB = sh + 16384 + ((wid << 2) << 9);

    // read bases (fragment-major, lane-linear)
    const int faA = ((wr << 1) << 2);     // A frag id base = mt0*4
    const int faB = ((wc << 2) << 2);     // B frag id base = nt0*4

    f32x16 acc[2][4];
#pragma unroll
    for (int i = 0; i < 2; ++i)
#pragma unroll
        for (int j = 0; j < 4; ++j)
#pragma unroll
            for (int e = 0; e < 16; ++e) acc[i][j][e] = 0.f;
    bf16x8 a[2][4], b[4][4];

    // prologue: stage tile0 fragment-major (8 gloads), drain, publish
    {
#pragma unroll
        for (int i = 0; i < 4; ++i) {
            stage_frag(Abf, srowA, (i << 4) + skoff, ldsA + (i << 9));
            stage_frag(Wbf, srowB, (i << 4) + skoff, ldsB + (i << 9));
        }
        asm volatile("s_waitcnt vmcnt(0)" ::: "memory");
        __builtin_amdgcn_s_barrier();
    }

    for (int t = 0; t < NT; ++t) {
        const int q = t & 1;
        unsigned short* curA = sh + (q << 15);
        unsigned short* curB = curA + 16384;
        const int nq = (q ^ 1) << 15;
        const int k1 = ((t + 1) & 31) << 6;   // wrapped tail: garbage into dead buf

        // stage tile t+1 fragment-major (8 gloads; nxt freed at (t-1)-end barrier)
#pragma unroll
        for (int i = 0; i < 4; ++i) {
            stage_frag(Abf, srowA, k1 + (i << 4) + skoff, ldsA + nq + (i << 9));
            stage_frag(Wbf, srowB, k1 + (i << 4) + skoff, ldsB + nq + (i << 9));
        }

        // ---- fragment reads: lane-linear, conflict-free (24 x ds_read_b128)
#pragma unroll
        for (int nl = 0; nl < 4; ++nl)
#pragma unroll
            for (int s = 0; s < 4; ++s)
                b[nl][s] = *(const bf16x8*)(curB + (((faB + (nl << 2) + s) << 9))
                                                 + (lane << 3));
#pragma unroll
        for (int ml = 0; ml < 2; ++ml)
#pragma unroll
            for (int s = 0; s < 4; ++s)
                a[ml][s] = *(const bf16x8*)(curA + (((faA + (ml << 2) + s) << 9))
                                                 + (lane << 3));

        // ---- MFMA: 32 x 32x32x16 per wave
#pragma unroll
        for (int s = 0; s < 4; ++s)
#pragma unroll
            for (int ml = 0; ml < 2; ++ml)
#pragma unroll
                for (int nl = 0; nl < 4; ++nl)
                    acc[ml][nl] = __builtin_amdgcn_mfma_f32_32x32x16_bf16(
                        a[ml][s], b[nl][s], acc[ml][nl], 0, 0, 0);

        // tile-end: publish tile t+1 and release cur
        asm volatile("s_waitcnt vmcnt(0)" ::: "memory");
        __builtin_amdgcn_s_barrier();
    }

    // ---- fused LSTM epilogue (r17-verified 32x32 C/D layout) ----
    // col = lane&31, row = (reg&3) + 8*(reg>>2) + 4*(lane>>5); nl = gate.
    const int c0    = bcol + (wc << 7);
    const int hcol  = ((c0 >> 7) << 5) + l31;
    const float bs0 = bias[c0 +       l31];
    const float bs1 = bias[c0 +  32 + l31];
    const float bs2 = bias[c0 +  64 + l31];
    const float bs3 = bias[c0 +  96 + l31];
    const int rbase = brow + (wr << 6) + ((lane >> 5) << 2);
    const size_t P  = (size_t)B_ * H_;
#pragma unroll
    for (int mt = 0; mt < 2; ++mt) {
#pragma unroll
        for (int r = 0; r < 16; ++r) {
            const int row = rbase + mt * 32 + (r & 3) + ((r >> 2) << 3);
            const size_t base = (size_t)row * H_ + hcol;
            float fg = sigf(acc[mt][0][r] + bs0);
            float ig = sigf(acc[mt][1][r] + bs1);
            float kg = tanhfast(acc[mt][2][r] + bs2);
            float og = sigf(acc[mt][3][r] + bs3);
            float cv = c[base];
            float cn = fg * cv + ig * kg;
            float hn = og * tanhfast(cn);
            out[base]         = og;
            out[P + base]     = cn;
            out[2 * P + base] = hn;
        }
    }
}

// ---------------------------------------------------------------- launch
extern "C" void kernel_launch(void* const* d_in, const int* in_sizes, int n_in,
                              void* d_out, int out_size, void* d_ws, size_t ws_size,
                              hipStream_t stream)
{
    const float* x  = (const float*)d_in[0];
    const float* c  = (const float*)d_in[1];
    const float* h  = (const float*)d_in[2];
    const float* Wx = (const float*)d_in[3];
    const float* bx = (const float*)d_in[4];
    const float* Wh = (const float*)d_in[5];
    const float* bh = (const float*)d_in[6];

    unsigned short* Abf  = (unsigned short*)((char*)d_ws + OFF_A);
    unsigned short* Wbf  = (unsigned short*)((char*)d_ws + OFF_W);
    float*          bias = (float*)((char*)d_ws + OFF_BI);
    float*          out  = (float*)d_out;

    cvt_kernel<<<40960, 256, 0, stream>>>(x, h, Wx, Wh, Abf, Wbf);
    bias_kernel<<<16, 256, 0, stream>>>(bx, bh, bias);
    gemm_lstm<<<(M / 256) * (N / 256), 512, 0, stream>>>(
        Abf, Wbf, bias, c, out);
}